// Round 2
// baseline (1279.361 us; speedup 1.0000x reference)
//
#include <hip/hip_runtime.h>
#include <hip/hip_bf16.h>

#define B 512
#define D 128
#define K 131072
#define TEMP 0.07f

// ws layout in floats
#define INVN_OFF 0
#define Z0_OFF   (K)
#define Z1_OFF   (Z0_OFF + B*D)
#define P0_OFF   (Z1_OFF + B*D)
#define P1_OFF   (P0_OFF + B*D)
#define PVAL_OFF (P1_OFF + B*D)          // 2*B*512 floats
#define PIDX_OFF (PVAL_OFF + 2*B*512)    // 2*B*512 ints
#define IDX_OFF  (PIDX_OFF + 2*B*512)    // 1024 ints
#define LP_OFF   (IDX_OFF + 1024)        // 1024 floats

// Normalize rows of z0, z1, p0, p1 (each B x D) into ws.
__global__ __launch_bounds__(128) void rownorm_k(
    const float* __restrict__ p0, const float* __restrict__ p1,
    const float* __restrict__ z0, const float* __restrict__ z1,
    float* __restrict__ w) {
  int row = blockIdx.x & (B - 1);
  int which = blockIdx.x >> 9;  // 0..3
  const float* src; float* dst;
  switch (which) {
    case 0: src = z0; dst = w + Z0_OFF; break;
    case 1: src = z1; dst = w + Z1_OFF; break;
    case 2: src = p0; dst = w + P0_OFF; break;
    default: src = p1; dst = w + P1_OFF; break;
  }
  int tid = threadIdx.x;
  float v = src[row * D + tid];
  float s = v * v;
  #pragma unroll
  for (int o = 32; o; o >>= 1) s += __shfl_xor(s, o);
  __shared__ float sm[2];
  if ((tid & 63) == 0) sm[tid >> 6] = s;
  __syncthreads();
  float inv = rsqrtf(sm[0] + sm[1]);
  dst[row * D + tid] = v * inv;
}

// Column inverse norms of queue; write new_queue (f32) and new_queue_id (f32).
__global__ __launch_bounds__(256) void colq_k(
    const float* __restrict__ q, const int* __restrict__ qid,
    const int* __restrict__ ids, const float* __restrict__ w_z0,
    float* __restrict__ invn, float* __restrict__ out) {
  int k = blockIdx.x * 256 + threadIdx.x;
  float s = 0.f;
  for (int d = 0; d < D; d++) { float v = q[d * K + k]; s = fmaf(v, v, s); }
  float inv = rsqrtf(s);
  invn[k] = inv;
  float* oq = out + 1;
  if (k < B) {
    for (int d = 0; d < D; d++) oq[d * K + k] = w_z0[k * D + d];
  } else {
    for (int d = 0; d < D; d++) oq[d * K + k] = q[d * K + k] * inv;
  }
  int idv = (k < B) ? ids[k] : qid[k];
  out[1 + D * K + k] = (float)idv;
}

// NN search: block = 256 cols x 64 rows tile. Partial argmax per (view, b, kblock).
__global__ __launch_bounds__(256) void nnsearch_k(
    const float* __restrict__ q, const float* __restrict__ invn,
    const int* __restrict__ qid, const int* __restrict__ ids,
    const float* __restrict__ w, float* __restrict__ pval,
    int* __restrict__ pidx) {
  __shared__ float zt[64][D];
  __shared__ int idt[64];
  __shared__ float cv[256];
  __shared__ int ci[256];
  int tid = threadIdx.x;
  int kb = blockIdx.x;   // 0..511
  int bt = blockIdx.y;   // 0..7
  int v  = blockIdx.z;   // 0..1
  const float* z = w + (v ? Z1_OFF : Z0_OFF) + bt * 64 * D;
  for (int i = tid; i < 64 * D; i += 256) zt[i >> 7][i & (D - 1)] = z[i];
  if (tid < 64) idt[tid] = ids[bt * 64 + tid];
  __syncthreads();
  int k = kb * 256 + tid;
  float acc[64];
  #pragma unroll
  for (int b = 0; b < 64; b++) acc[b] = 0.f;
  for (int d0 = 0; d0 < D; d0 += 16) {
    float qv[16];
    #pragma unroll
    for (int i = 0; i < 16; i++) qv[i] = q[(d0 + i) * K + k];
    #pragma unroll
    for (int b = 0; b < 64; b++) {
      const float* zr = &zt[b][d0];
      #pragma unroll
      for (int i = 0; i < 16; i++) acc[b] = fmaf(qv[i], zr[i], acc[b]);
    }
  }
  float inv = invn[k];
  int myqid = qid[k];
  int wave = tid >> 6, lane = tid & 63;
  #pragma unroll
  for (int b = 0; b < 64; b++) {
    float sim = (myqid == idt[b]) ? -1.0f : acc[b] * inv;
    int bi = k;
    #pragma unroll
    for (int o = 32; o; o >>= 1) {
      float ov = __shfl_xor(sim, o);
      int oi = __shfl_xor(bi, o);
      if (ov > sim || (ov == sim && oi < bi)) { sim = ov; bi = oi; }
    }
    if (lane == 0) { cv[wave * 64 + b] = sim; ci[wave * 64 + b] = bi; }
  }
  __syncthreads();
  if (tid < 64) {
    float best = cv[tid]; int bi = ci[tid];
    #pragma unroll
    for (int wv = 1; wv < 4; wv++) {
      float ov = cv[wv * 64 + tid]; int oi = ci[wv * 64 + tid];
      if (ov > best || (ov == best && oi < bi)) { best = ov; bi = oi; }
    }
    int bg = bt * 64 + tid;
    int off = (v * B + bg) * 512 + kb;
    pval[off] = best; pidx[off] = bi;
  }
}

// Reduce 512 partials per (view, b) -> final NN index.
__global__ __launch_bounds__(256) void nnreduce_k(
    const float* __restrict__ pval, const int* __restrict__ pidx,
    int* __restrict__ idxout) {
  int vb = blockIdx.x;
  int tid = threadIdx.x;
  const float* pv = pval + vb * 512;
  const int* pi = pidx + vb * 512;
  float best = -2.f; int bi = 0x7fffffff;
  for (int j = tid; j < 512; j += 256) {
    float vv = pv[j]; int ii = pi[j];
    if (vv > best || (vv == best && ii < bi)) { best = vv; bi = ii; }
  }
  #pragma unroll
  for (int o = 32; o; o >>= 1) {
    float ov = __shfl_xor(best, o); int oi = __shfl_xor(bi, o);
    if (ov > best || (ov == best && oi < bi)) { best = ov; bi = oi; }
  }
  __shared__ float sv[4]; __shared__ int si[4];
  if ((tid & 63) == 0) { sv[tid >> 6] = best; si[tid >> 6] = bi; }
  __syncthreads();
  if (tid == 0) {
    for (int wv = 1; wv < 4; wv++) {
      if (sv[wv] > best || (sv[wv] == best && si[wv] < bi)) { best = sv[wv]; bi = si[wv]; }
    }
    idxout[vb] = bi;
  }
}

// Per-row log-softmax diagonal. blockIdx.x = i (0..511), blockIdx.y = v.
// v=0: predicted=p0, nn from idx1; v=1: predicted=p1, nn from idx0.
__global__ __launch_bounds__(256) void loss_k(
    const float* __restrict__ q, const float* __restrict__ invn,
    const int* __restrict__ idxout, const float* __restrict__ w,
    float* __restrict__ lpart) {
  int i = blockIdx.x; int v = blockIdx.y;
  int tid = threadIdx.x;
  __shared__ float nn[D];
  __shared__ float red[4];
  __shared__ float red2[4];
  __shared__ float sdiag;
  int nnidx = idxout[(v ? 0 : 1) * B + i];
  if (tid < D) nn[tid] = q[tid * K + nnidx] * invn[nnidx];
  __syncthreads();
  const float* p = w + (v ? P1_OFF : P0_OFF);
  const float* r0 = p + tid * D;
  const float* r1 = p + (tid + 256) * D;
  float a0 = 0.f, a1 = 0.f;
  for (int d = 0; d < D; d += 4) {
    float4 x0 = *(const float4*)(r0 + d);
    float4 x1 = *(const float4*)(r1 + d);
    float n0 = nn[d], n1 = nn[d + 1], n2 = nn[d + 2], n3 = nn[d + 3];
    a0 = fmaf(x0.x, n0, a0); a0 = fmaf(x0.y, n1, a0);
    a0 = fmaf(x0.z, n2, a0); a0 = fmaf(x0.w, n3, a0);
    a1 = fmaf(x1.x, n0, a1); a1 = fmaf(x1.y, n1, a1);
    a1 = fmaf(x1.z, n2, a1); a1 = fmaf(x1.w, n3, a1);
  }
  float l0 = a0 * (1.0f / TEMP), l1 = a1 * (1.0f / TEMP);
  if (tid == (i & 255)) sdiag = (i < 256) ? l0 : l1;
  float m = fmaxf(l0, l1);
  #pragma unroll
  for (int o = 32; o; o >>= 1) m = fmaxf(m, __shfl_xor(m, o));
  if ((tid & 63) == 0) red[tid >> 6] = m;
  __syncthreads();
  m = fmaxf(fmaxf(red[0], red[1]), fmaxf(red[2], red[3]));
  float e = expf(l0 - m) + expf(l1 - m);
  #pragma unroll
  for (int o = 32; o; o >>= 1) e += __shfl_xor(e, o);
  if ((tid & 63) == 0) red2[tid >> 6] = e;
  __syncthreads();
  if (tid == 0) {
    float s = red2[0] + red2[1] + red2[2] + red2[3];
    lpart[v * B + i] = sdiag - (m + logf(s));
  }
}

// Final: loss = -(sum of 1024 partials)/1024 ; also write new_ptr.
__global__ __launch_bounds__(256) void final_k(
    const float* __restrict__ lpart, float* __restrict__ out) {
  int tid = threadIdx.x;
  float s = lpart[tid] + lpart[tid + 256] + lpart[tid + 512] + lpart[tid + 768];
  #pragma unroll
  for (int o = 32; o; o >>= 1) s += __shfl_xor(s, o);
  __shared__ float sm[4];
  if ((tid & 63) == 0) sm[tid >> 6] = s;
  __syncthreads();
  if (tid == 0) {
    float total = sm[0] + sm[1] + sm[2] + sm[3];
    out[0] = -total * (1.0f / 1024.0f);
    out[1 + D * K + K] = 512.0f;
  }
}

extern "C" void kernel_launch(void* const* d_in, const int* in_sizes, int n_in,
                              void* d_out, int out_size, void* d_ws, size_t ws_size,
                              hipStream_t stream) {
  const float* p0 = (const float*)d_in[0];
  const float* p1 = (const float*)d_in[1];
  const float* z0 = (const float*)d_in[2];
  const float* z1 = (const float*)d_in[3];
  const float* q  = (const float*)d_in[4];
  const int* qid  = (const int*)d_in[5];
  const int* ids  = (const int*)d_in[6];
  float* out = (float*)d_out;
  float* w = (float*)d_ws;
  float* invn = w + INVN_OFF;
  float* pval = w + PVAL_OFF;
  int* pidx   = (int*)(w + PIDX_OFF);
  int* idxout = (int*)(w + IDX_OFF);
  float* lpart = w + LP_OFF;

  rownorm_k<<<2048, 128, 0, stream>>>(p0, p1, z0, z1, w);
  colq_k<<<K / 256, 256, 0, stream>>>(q, qid, ids, w + Z0_OFF, invn, out);
  dim3 g(512, 8, 2);
  nnsearch_k<<<g, 256, 0, stream>>>(q, invn, qid, ids, w, pval, pidx);
  nnreduce_k<<<1024, 256, 0, stream>>>(pval, pidx, idxout);
  dim3 gl(B, 2);
  loss_k<<<gl, 256, 0, stream>>>(q, invn, idxout, w, lpart);
  final_k<<<1, 256, 0, stream>>>(lpart, out);
}

// Round 3
// 187.629 us; speedup vs baseline: 6.8186x; 6.8186x over previous
//
#include <hip/hip_runtime.h>
#include <hip/hip_bf16.h>

typedef _Float16 half8 __attribute__((ext_vector_type(8)));
typedef float f32x4 __attribute__((ext_vector_type(4)));

#define B 512
#define D 128
#define K 131072
#define TEMP 0.07f
#define NKB 256      // k-blocks in nnsearch grid
#define KT_PER 32    // 16-wide k-tiles per block (512 cols)

// ws layout in float units
#define INVN_OFF 0
#define Z0_OFF   131072
#define Z1_OFF   196608
#define P0_OFF   262144
#define P1_OFF   327680
#define ZF16_OFF 393216                 // 1024*128 halves = 65536 floats
#define QA_OFF   458752                 // K*D halves = 8388608 floats
#define PVAL_OFF 8847360                // 1024*256 floats
#define PIDX_OFF 9109504                // 1024*256 ints
#define IDX_OFF  9371648                // 1024 ints
#define LP_OFF   9372672                // 1024 floats

// Normalize rows of z0, z1, p0, p1 (each B x D) into ws; also z in f16.
__global__ __launch_bounds__(128) void rownorm_k(
    const float* __restrict__ p0, const float* __restrict__ p1,
    const float* __restrict__ z0, const float* __restrict__ z1,
    float* __restrict__ w, _Float16* __restrict__ zf16) {
  int row = blockIdx.x & (B - 1);
  int which = blockIdx.x >> 9;  // 0..3
  const float* src; float* dst;
  switch (which) {
    case 0: src = z0; dst = w + Z0_OFF; break;
    case 1: src = z1; dst = w + Z1_OFF; break;
    case 2: src = p0; dst = w + P0_OFF; break;
    default: src = p1; dst = w + P1_OFF; break;
  }
  int tid = threadIdx.x;
  float v = src[row * D + tid];
  float s = v * v;
  #pragma unroll
  for (int o = 32; o; o >>= 1) s += __shfl_xor(s, o);
  __shared__ float sm[2];
  if ((tid & 63) == 0) sm[tid >> 6] = s;
  __syncthreads();
  float inv = rsqrtf(sm[0] + sm[1]);
  float nv = v * inv;
  dst[row * D + tid] = nv;
  if (which < 2) zf16[(which * B + row) * D + tid] = (_Float16)nv;
}

// Column inverse norms of queue; write new_queue (f32) and new_queue_id (f32).
__global__ __launch_bounds__(256) void colq_k(
    const float* __restrict__ q, const int* __restrict__ qid,
    const int* __restrict__ ids, const float* __restrict__ w_z0,
    float* __restrict__ invn, float* __restrict__ out) {
  int k = blockIdx.x * 256 + threadIdx.x;
  float s = 0.f;
  for (int d = 0; d < D; d++) { float v = q[d * K + k]; s = fmaf(v, v, s); }
  float inv = rsqrtf(s);
  invn[k] = inv;
  float* oq = out + 1;
  if (k < B) {
    for (int d = 0; d < D; d++) oq[d * K + k] = w_z0[k * D + d];
  } else {
    for (int d = 0; d < D; d++) oq[d * K + k] = q[d * K + k] * inv;
  }
  int idv = (k < B) ? ids[k] : qid[k];
  out[1 + D * K + k] = (float)idv;
}

// Pack normalized queue into fragment-major f16 layout for MFMA A-operand.
// frag element i of lane l (g=l>>4, c=l&15) for tile kt, dchunk dc:
//   k = kt*16 + c ; d = g*4 + (i&3) + ((i>>2)<<4) + dc*32
__global__ __launch_bounds__(256) void qprep_k(
    const float* __restrict__ q, const float* __restrict__ invn,
    _Float16* __restrict__ qA) {
  int kt = blockIdx.x;
  int tid = threadIdx.x;
  int dc = tid >> 6, l = tid & 63;
  int g = l >> 4, c = l & 15;
  int k = kt * 16 + c;
  float inv = invn[k];
  half8 f;
  #pragma unroll
  for (int i = 0; i < 8; i++) {
    int d = g * 4 + (i & 3) + ((i >> 2) << 4) + dc * 32;
    f[i] = (_Float16)(q[d * K + k] * inv);
  }
  *(half8*)(qA + (size_t)((kt * 4 + dc) * 64 + l) * 8) = f;
}

// MFMA NN search. Swapped operands: M = queue index k, N = z-row.
// Block = 4 waves; wave owns 64 z-rows (B-frags register-resident),
// sweeps 512 queue columns. Per-lane running masked argmax, then
// 2-shuffle cross-lane reduce. Partial (val,idx) per (row, kblock).
__global__ __launch_bounds__(256) void nnsearch_k(
    const _Float16* __restrict__ qA, const _Float16* __restrict__ zf16,
    const int* __restrict__ qid, const int* __restrict__ ids,
    float* __restrict__ pval, int* __restrict__ pidx) {
  int tid = threadIdx.x;
  int kb = blockIdx.x;   // 0..NKB-1
  int rg = blockIdx.y;   // 0..3 (256 rows each)
  int wave = tid >> 6, lane = tid & 63;
  int g = lane >> 4, c = lane & 15;
  int rowbase = rg * 256 + wave * 64;

  half8 bf[4][4];
  int myid[4];
  #pragma unroll
  for (int nt = 0; nt < 4; nt++) {
    int row = rowbase + nt * 16 + c;
    myid[nt] = ids[row & (B - 1)];
    #pragma unroll
    for (int dc = 0; dc < 4; dc++) {
      const _Float16* zr = zf16 + row * D + dc * 32 + g * 4;
      half8 f;
      #pragma unroll
      for (int i = 0; i < 8; i++) f[i] = zr[(i & 3) + ((i >> 2) << 4)];
      bf[nt][dc] = f;
    }
  }

  float bestv[4] = {-2.f, -2.f, -2.f, -2.f};
  int bestk[4] = {0, 0, 0, 0};
  int kt0 = kb * KT_PER;
  for (int kt = 0; kt < KT_PER; kt++) {
    int ktg = kt0 + kt;
    half8 af[4];
    #pragma unroll
    for (int dc = 0; dc < 4; dc++)
      af[dc] = *(const half8*)(qA + (size_t)((ktg * 4 + dc) * 64 + lane) * 8);
    int4 q4 = *(const int4*)(qid + ktg * 16 + g * 4);
    #pragma unroll
    for (int nt = 0; nt < 4; nt++) {
      f32x4 acc = {0.f, 0.f, 0.f, 0.f};
      #pragma unroll
      for (int dc = 0; dc < 4; dc++)
        acc = __builtin_amdgcn_mfma_f32_16x16x32_f16(af[dc], bf[nt][dc], acc, 0, 0, 0);
      int kbase2 = ktg * 16 + g * 4;
      #pragma unroll
      for (int r = 0; r < 4; r++) {
        float s = acc[r];
        int qv = (r == 0) ? q4.x : (r == 1) ? q4.y : (r == 2) ? q4.z : q4.w;
        if (qv == myid[nt]) s = -1.0f;
        if (s > bestv[nt]) { bestv[nt] = s; bestk[nt] = kbase2 + r; }
      }
    }
  }

  #pragma unroll
  for (int nt = 0; nt < 4; nt++) {
    float v = bestv[nt]; int kx = bestk[nt];
    #pragma unroll
    for (int o = 16; o <= 32; o <<= 1) {
      float ov = __shfl_xor(v, o); int ok = __shfl_xor(kx, o);
      if (ov > v || (ov == v && ok < kx)) { v = ov; kx = ok; }
    }
    if (g == 0) {
      int row = rowbase + nt * 16 + c;
      pval[row * NKB + kb] = v;
      pidx[row * NKB + kb] = kx;
    }
  }
}

// Reduce NKB partials per row -> final NN index. One block per row.
__global__ __launch_bounds__(256) void nnreduce_k(
    const float* __restrict__ pval, const int* __restrict__ pidx,
    int* __restrict__ idxout) {
  int row = blockIdx.x;
  int tid = threadIdx.x;
  float v = pval[row * NKB + tid];
  int kx = pidx[row * NKB + tid];
  #pragma unroll
  for (int o = 32; o; o >>= 1) {
    float ov = __shfl_xor(v, o); int ok = __shfl_xor(kx, o);
    if (ov > v || (ov == v && ok < kx)) { v = ov; kx = ok; }
  }
  __shared__ float sv[4]; __shared__ int si[4];
  if ((tid & 63) == 0) { sv[tid >> 6] = v; si[tid >> 6] = kx; }
  __syncthreads();
  if (tid == 0) {
    for (int wv = 1; wv < 4; wv++) {
      if (sv[wv] > v || (sv[wv] == v && si[wv] < kx)) { v = sv[wv]; kx = si[wv]; }
    }
    idxout[row] = kx;
  }
}

// Per-row log-softmax diagonal. blockIdx.x = i (0..511), blockIdx.y = v.
// v=0: predicted=p0, nn from z1 search (rows 512..1023); v=1: p1, nn from z0.
__global__ __launch_bounds__(256) void loss_k(
    const float* __restrict__ q, const float* __restrict__ invn,
    const int* __restrict__ idxout, const float* __restrict__ w,
    float* __restrict__ lpart) {
  int i = blockIdx.x; int v = blockIdx.y;
  int tid = threadIdx.x;
  __shared__ float nn[D];
  __shared__ float red[4];
  __shared__ float red2[4];
  __shared__ float sdiag;
  int nnidx = idxout[(v ? 0 : B) + i];
  if (tid < D) nn[tid] = q[tid * K + nnidx] * invn[nnidx];
  __syncthreads();
  const float* p = w + (v ? P1_OFF : P0_OFF);
  const float* r0 = p + tid * D;
  const float* r1 = p + (tid + 256) * D;
  float a0 = 0.f, a1 = 0.f;
  for (int d = 0; d < D; d += 4) {
    float4 x0 = *(const float4*)(r0 + d);
    float4 x1 = *(const float4*)(r1 + d);
    float n0 = nn[d], n1 = nn[d + 1], n2 = nn[d + 2], n3 = nn[d + 3];
    a0 = fmaf(x0.x, n0, a0); a0 = fmaf(x0.y, n1, a0);
    a0 = fmaf(x0.z, n2, a0); a0 = fmaf(x0.w, n3, a0);
    a1 = fmaf(x1.x, n0, a1); a1 = fmaf(x1.y, n1, a1);
    a1 = fmaf(x1.z, n2, a1); a1 = fmaf(x1.w, n3, a1);
  }
  float l0 = a0 * (1.0f / TEMP), l1 = a1 * (1.0f / TEMP);
  if (tid == (i & 255)) sdiag = (i < 256) ? l0 : l1;
  float m = fmaxf(l0, l1);
  #pragma unroll
  for (int o = 32; o; o >>= 1) m = fmaxf(m, __shfl_xor(m, o));
  if ((tid & 63) == 0) red[tid >> 6] = m;
  __syncthreads();
  m = fmaxf(fmaxf(red[0], red[1]), fmaxf(red[2], red[3]));
  float e = expf(l0 - m) + expf(l1 - m);
  #pragma unroll
  for (int o = 32; o; o >>= 1) e += __shfl_xor(e, o);
  if ((tid & 63) == 0) red2[tid >> 6] = e;
  __syncthreads();
  if (tid == 0) {
    float s = red2[0] + red2[1] + red2[2] + red2[3];
    lpart[v * B + i] = sdiag - (m + logf(s));
  }
}

// Final: loss = -(sum of 1024 partials)/1024 ; also write new_ptr.
__global__ __launch_bounds__(256) void final_k(
    const float* __restrict__ lpart, float* __restrict__ out) {
  int tid = threadIdx.x;
  float s = lpart[tid] + lpart[tid + 256] + lpart[tid + 512] + lpart[tid + 768];
  #pragma unroll
  for (int o = 32; o; o >>= 1) s += __shfl_xor(s, o);
  __shared__ float sm[4];
  if ((tid & 63) == 0) sm[tid >> 6] = s;
  __syncthreads();
  if (tid == 0) {
    float total = sm[0] + sm[1] + sm[2] + sm[3];
    out[0] = -total * (1.0f / 1024.0f);
    out[1 + D * K + K] = 512.0f;
  }
}

extern "C" void kernel_launch(void* const* d_in, const int* in_sizes, int n_in,
                              void* d_out, int out_size, void* d_ws, size_t ws_size,
                              hipStream_t stream) {
  const float* p0 = (const float*)d_in[0];
  const float* p1 = (const float*)d_in[1];
  const float* z0 = (const float*)d_in[2];
  const float* z1 = (const float*)d_in[3];
  const float* q  = (const float*)d_in[4];
  const int* qid  = (const int*)d_in[5];
  const int* ids  = (const int*)d_in[6];
  float* out = (float*)d_out;
  float* w = (float*)d_ws;
  float* invn = w + INVN_OFF;
  _Float16* zf16 = (_Float16*)(w + ZF16_OFF);
  _Float16* qA   = (_Float16*)(w + QA_OFF);
  float* pval = w + PVAL_OFF;
  int* pidx   = (int*)(w + PIDX_OFF);
  int* idxout = (int*)(w + IDX_OFF);
  float* lpart = w + LP_OFF;

  rownorm_k<<<2048, 128, 0, stream>>>(p0, p1, z0, z1, w, zf16);
  colq_k<<<K / 256, 256, 0, stream>>>(q, qid, ids, w + Z0_OFF, invn, out);
  qprep_k<<<K / 16, 256, 0, stream>>>(q, invn, qA);
  dim3 g(NKB, 4);
  nnsearch_k<<<g, 256, 0, stream>>>(qA, zf16, qid, ids, pval, pidx);
  nnreduce_k<<<1024, 256, 0, stream>>>(pval, pidx, idxout);
  dim3 gl(B, 2);
  loss_k<<<gl, 256, 0, stream>>>(q, invn, idxout, w, lpart);
  final_k<<<1, 256, 0, stream>>>(lpart, out);
}

// Round 4
// 163.144 us; speedup vs baseline: 7.8419x; 1.1501x over previous
//
#include <hip/hip_runtime.h>
#include <hip/hip_bf16.h>

typedef _Float16 half8 __attribute__((ext_vector_type(8)));
typedef _Float16 half4 __attribute__((ext_vector_type(4)));
typedef float f32x4 __attribute__((ext_vector_type(4)));

#define B 512
#define D 128
#define K 131072
#define TEMP 0.07f
#define NKB 512      // k-blocks in nnsearch grid
#define KT_PER 16    // 16-wide k-tiles per block (256 cols)

// ws layout in float units
#define INVN_OFF 0
#define Z0_OFF   131072
#define Z1_OFF   196608
#define P0_OFF   262144
#define P1_OFF   327680
#define ZF16_OFF 393216                 // 1024*128 halves = 65536 floats
#define QA_OFF   458752                 // K*D halves = 8388608 floats
#define PVAL_OFF 8847360                // 1024*512 u32
#define IDX_OFF  9371648                // 1024 ints
#define LP_OFF   9372672                // 1024 floats

// Normalize rows of z0, z1, p0, p1 (each B x D) into ws; also z in f16.
__global__ __launch_bounds__(128) void rownorm_k(
    const float* __restrict__ p0, const float* __restrict__ p1,
    const float* __restrict__ z0, const float* __restrict__ z1,
    float* __restrict__ w, _Float16* __restrict__ zf16) {
  int row = blockIdx.x & (B - 1);
  int which = blockIdx.x >> 9;  // 0..3
  const float* src; float* dst;
  switch (which) {
    case 0: src = z0; dst = w + Z0_OFF; break;
    case 1: src = z1; dst = w + Z1_OFF; break;
    case 2: src = p0; dst = w + P0_OFF; break;
    default: src = p1; dst = w + P1_OFF; break;
  }
  int tid = threadIdx.x;
  float v = src[row * D + tid];
  float s = v * v;
  #pragma unroll
  for (int o = 32; o; o >>= 1) s += __shfl_xor(s, o);
  __shared__ float sm[2];
  if ((tid & 63) == 0) sm[tid >> 6] = s;
  __syncthreads();
  float inv = rsqrtf(sm[0] + sm[1]);
  float nv = v * inv;
  dst[row * D + tid] = nv;
  if (which < 2) zf16[(which * B + row) * D + tid] = (_Float16)nv;
}

// Fused: column inverse norms, new_queue (f32) + new_queue_id writes, and
// fragment-major f16 qA pack (MFMA A-operand layout), reading q once (2nd
// pass is L2-hot on the block's 128KB tile).
// qA frag element i of lane l (g=l>>4, c=l&15), tile kt, dchunk dc:
//   k = kt*16 + c ; d = g*4 + (i&3) + ((i>>2)<<4) + dc*32
__global__ __launch_bounds__(256) void colq_k(
    const float* __restrict__ q, const int* __restrict__ qid,
    const int* __restrict__ ids, const float* __restrict__ w_z0,
    float* __restrict__ invn, float* __restrict__ out,
    _Float16* __restrict__ qA) {
  int k = blockIdx.x * 256 + threadIdx.x;
  float s = 0.f;
  for (int d = 0; d < D; d++) { float v = q[d * K + k]; s = fmaf(v, v, s); }
  float inv = rsqrtf(s);
  invn[k] = inv;
  out[1 + D * K + k] = (float)((k < B) ? ids[k] : qid[k]);
  float* oq = out + 1;
  int kt = k >> 4, c = k & 15;
  bool small = (k < B);
  #pragma unroll
  for (int dc = 0; dc < 4; dc++) {
    #pragma unroll
    for (int g = 0; g < 4; g++) {
      half8 f;
      #pragma unroll
      for (int i = 0; i < 8; i++) {
        int d = g * 4 + (i & 3) + ((i >> 2) << 4) + dc * 32;
        float qv = q[d * K + k] * inv;
        f[i] = (_Float16)qv;
        oq[d * K + k] = small ? w_z0[k * D + d] : qv;
      }
      *(half8*)(qA + (size_t)((kt * 4 + dc) * 64 + g * 16 + c) * 8) = f;
    }
  }
}

#define LOADAF(AF, Q4, KTG) do { \
  _Pragma("unroll") \
  for (int dc = 0; dc < 4; dc++) \
    AF[dc] = *(const half8*)(qA + (size_t)(((KTG) * 4 + dc) * 64 + lane) * 8); \
  Q4 = *(const int4*)(qid + (KTG) * 16 + g * 4); \
} while (0)

#define PROCESS(AF, Q4, KTG) do { \
  int kbase = (KTG) * 16 + g * 4; \
  unsigned idxc0 = 0x1FFFFu - (unsigned)kbase; \
  _Pragma("unroll") \
  for (int nt = 0; nt < 4; nt++) { \
    f32x4 acc = {0.f, 0.f, 0.f, 0.f}; \
    _Pragma("unroll") \
    for (int dc = 0; dc < 4; dc++) \
      acc = __builtin_amdgcn_mfma_f32_16x16x32_f16(AF[dc], bf[nt][dc], acc, 0, 0, 0); \
    _Pragma("unroll") \
    for (int r = 0; r < 4; r++) { \
      float sv_ = acc[r]; \
      int qv_ = (r == 0) ? Q4.x : (r == 1) ? Q4.y : (r == 2) ? Q4.z : Q4.w; \
      float t_ = fmaf(sv_, 0.5f, 3.0f); \
      unsigned pk_ = ((__float_as_uint(t_) << 9) & 0xFFFE0000u) | (idxc0 - r); \
      pk_ = (qv_ == myid[nt]) ? 0u : pk_; \
      best[nt] = best[nt] > pk_ ? best[nt] : pk_; \
    } \
  } \
} while (0)

// MFMA NN search. M = queue index k, N = z-row. Wave owns 64 z-rows
// (B-frags register-resident). Packed-u32 masked argmax; 2-deep pipeline
// on the qA fragment loads.
__global__ __launch_bounds__(256) void nnsearch_k(
    const _Float16* __restrict__ qA, const _Float16* __restrict__ zf16,
    const int* __restrict__ qid, const int* __restrict__ ids,
    unsigned* __restrict__ pbest) {
  int tid = threadIdx.x;
  int kb = blockIdx.x;   // 0..NKB-1
  int rg = blockIdx.y;   // 0..3 (256 rows each)
  int wave = tid >> 6, lane = tid & 63;
  int g = lane >> 4, c = lane & 15;
  int rowbase = rg * 256 + wave * 64;

  half8 bf[4][4];
  int myid[4];
  #pragma unroll
  for (int nt = 0; nt < 4; nt++) {
    int row = rowbase + nt * 16 + c;
    myid[nt] = ids[row & (B - 1)];
    #pragma unroll
    for (int dc = 0; dc < 4; dc++) {
      const _Float16* zr = zf16 + row * D + dc * 32 + g * 4;
      half4 lo = *(const half4*)zr;
      half4 hi = *(const half4*)(zr + 16);
      half8 f = {lo[0], lo[1], lo[2], lo[3], hi[0], hi[1], hi[2], hi[3]};
      bf[nt][dc] = f;
    }
  }

  unsigned best[4] = {0u, 0u, 0u, 0u};
  int kt0 = kb * KT_PER;
  half8 afA[4], afB[4];
  int4 q4A, q4B;
  LOADAF(afA, q4A, kt0);
  for (int kt = 0; kt < KT_PER; kt += 2) {
    LOADAF(afB, q4B, kt0 + kt + 1);
    PROCESS(afA, q4A, kt0 + kt);
    if (kt + 2 < KT_PER) LOADAF(afA, q4A, kt0 + kt + 2);
    PROCESS(afB, q4B, kt0 + kt + 1);
  }

  #pragma unroll
  for (int nt = 0; nt < 4; nt++) {
    unsigned v = best[nt];
    unsigned o1 = __shfl_xor(v, 16); v = v > o1 ? v : o1;
    unsigned o2 = __shfl_xor(v, 32); v = v > o2 ? v : o2;
    if (g == 0) {
      int row = rowbase + nt * 16 + c;
      pbest[row * NKB + kb] = v;
    }
  }
}

// Reduce NKB packed partials per row -> final NN index.
__global__ __launch_bounds__(256) void nnreduce_k(
    const unsigned* __restrict__ pbest, int* __restrict__ idxout) {
  int row = blockIdx.x;
  int tid = threadIdx.x;
  const unsigned* p = pbest + row * NKB;
  unsigned v = p[tid], u = p[tid + 256];
  v = v > u ? v : u;
  #pragma unroll
  for (int o = 32; o; o >>= 1) {
    unsigned ov = __shfl_xor(v, o);
    v = v > ov ? v : ov;
  }
  __shared__ unsigned sv[4];
  if ((tid & 63) == 0) sv[tid >> 6] = v;
  __syncthreads();
  if (tid == 0) {
    #pragma unroll
    for (int wv = 1; wv < 4; wv++) v = v > sv[wv] ? v : sv[wv];
    idxout[row] = (int)(0x1FFFFu - (v & 0x1FFFFu));
  }
}

// Loss: block handles 8 rows (i0..i0+7) for view v. Thread owns columns
// j=tid and j+256 of the 512-wide logits row.
__global__ __launch_bounds__(256) void loss_k(
    const float* __restrict__ q, const float* __restrict__ invn,
    const int* __restrict__ idxout, const float* __restrict__ w,
    float* __restrict__ lpart) {
  int i0 = blockIdx.x * 8;
  int v = blockIdx.y;
  int tid = threadIdx.x;
  __shared__ float nns[8][D];
  __shared__ float rm[8][4], re[8][4], sdlds[8];
  #pragma unroll
  for (int ii = 0; ii < 4; ii++) {
    int i = ii * 2 + (tid >> 7);
    int d = tid & 127;
    int nnidx = idxout[(v ? 0 : B) + i0 + i];
    nns[i][d] = q[(size_t)d * K + nnidx] * invn[nnidx];
  }
  __syncthreads();
  const float* pr = w + (v ? P1_OFF : P0_OFF);
  const float* r0 = pr + tid * D;
  const float* r1 = pr + (tid + 256) * D;
  float a0[8] = {0, 0, 0, 0, 0, 0, 0, 0};
  float a1[8] = {0, 0, 0, 0, 0, 0, 0, 0};
  for (int d = 0; d < D; d += 4) {
    float4 x0 = *(const float4*)(r0 + d);
    float4 x1 = *(const float4*)(r1 + d);
    #pragma unroll
    for (int i = 0; i < 8; i++) {
      float4 n = *(const float4*)&nns[i][d];
      a0[i] = fmaf(x0.x, n.x, a0[i]); a0[i] = fmaf(x0.y, n.y, a0[i]);
      a0[i] = fmaf(x0.z, n.z, a0[i]); a0[i] = fmaf(x0.w, n.w, a0[i]);
      a1[i] = fmaf(x1.x, n.x, a1[i]); a1[i] = fmaf(x1.y, n.y, a1[i]);
      a1[i] = fmaf(x1.z, n.z, a1[i]); a1[i] = fmaf(x1.w, n.w, a1[i]);
    }
  }
  #pragma unroll
  for (int i = 0; i < 8; i++) {
    a0[i] *= (1.0f / TEMP);
    a1[i] *= (1.0f / TEMP);
  }
  #pragma unroll
  for (int i = 0; i < 8; i++) {
    int ig = i0 + i;
    if ((ig & 256) == 0) { if (tid == ig) sdlds[i] = a0[i]; }
    else { if (tid == (ig & 255)) sdlds[i] = a1[i]; }
  }
  int wv = tid >> 6;
  #pragma unroll
  for (int i = 0; i < 8; i++) {
    float m = fmaxf(a0[i], a1[i]);
    #pragma unroll
    for (int o = 32; o; o >>= 1) m = fmaxf(m, __shfl_xor(m, o));
    if ((tid & 63) == 0) rm[i][wv] = m;
  }
  __syncthreads();
  #pragma unroll
  for (int i = 0; i < 8; i++) {
    float m = fmaxf(fmaxf(rm[i][0], rm[i][1]), fmaxf(rm[i][2], rm[i][3]));
    float e = expf(a0[i] - m) + expf(a1[i] - m);
    #pragma unroll
    for (int o = 32; o; o >>= 1) e += __shfl_xor(e, o);
    if ((tid & 63) == 0) re[i][wv] = e;
  }
  __syncthreads();
  if (tid < 8) {
    int i = tid;
    float m = fmaxf(fmaxf(rm[i][0], rm[i][1]), fmaxf(rm[i][2], rm[i][3]));
    float s = re[i][0] + re[i][1] + re[i][2] + re[i][3];
    lpart[v * B + i0 + i] = sdlds[i] - m - logf(s);
  }
}

// Final: loss = -(sum of 1024 partials)/1024 ; also write new_ptr.
__global__ __launch_bounds__(256) void final_k(
    const float* __restrict__ lpart, float* __restrict__ out) {
  int tid = threadIdx.x;
  float s = lpart[tid] + lpart[tid + 256] + lpart[tid + 512] + lpart[tid + 768];
  #pragma unroll
  for (int o = 32; o; o >>= 1) s += __shfl_xor(s, o);
  __shared__ float sm[4];
  if ((tid & 63) == 0) sm[tid >> 6] = s;
  __syncthreads();
  if (tid == 0) {
    float total = sm[0] + sm[1] + sm[2] + sm[3];
    out[0] = -total * (1.0f / 1024.0f);
    out[1 + D * K + K] = 512.0f;
  }
}

extern "C" void kernel_launch(void* const* d_in, const int* in_sizes, int n_in,
                              void* d_out, int out_size, void* d_ws, size_t ws_size,
                              hipStream_t stream) {
  const float* p0 = (const float*)d_in[0];
  const float* p1 = (const float*)d_in[1];
  const float* z0 = (const float*)d_in[2];
  const float* z1 = (const float*)d_in[3];
  const float* q  = (const float*)d_in[4];
  const int* qid  = (const int*)d_in[5];
  const int* ids  = (const int*)d_in[6];
  float* out = (float*)d_out;
  float* w = (float*)d_ws;
  float* invn = w + INVN_OFF;
  _Float16* zf16 = (_Float16*)(w + ZF16_OFF);
  _Float16* qA   = (_Float16*)(w + QA_OFF);
  unsigned* pbest = (unsigned*)(w + PVAL_OFF);
  int* idxout = (int*)(w + IDX_OFF);
  float* lpart = w + LP_OFF;

  rownorm_k<<<2048, 128, 0, stream>>>(p0, p1, z0, z1, w, zf16);
  colq_k<<<K / 256, 256, 0, stream>>>(q, qid, ids, w + Z0_OFF, invn, out, qA);
  dim3 g(NKB, 4);
  nnsearch_k<<<g, 256, 0, stream>>>(qA, zf16, qid, ids, pbest);
  nnreduce_k<<<1024, 256, 0, stream>>>(pbest, idxout);
  dim3 gl(B / 8, 2);
  loss_k<<<gl, 256, 0, stream>>>(q, invn, idxout, w, lpart);
  final_k<<<1, 256, 0, stream>>>(lpart, out);
}

// Round 5
// 131.718 us; speedup vs baseline: 9.7129x; 1.2386x over previous
//
#include <hip/hip_runtime.h>
#include <hip/hip_bf16.h>

typedef _Float16 half8 __attribute__((ext_vector_type(8)));
typedef _Float16 half4 __attribute__((ext_vector_type(4)));
typedef float f32x4 __attribute__((ext_vector_type(4)));

#define B 512
#define D 128
#define K 131072
#define TEMP 0.07f
#define NKB 512      // k-blocks in nnsearch grid
#define KT_PER 16    // 16-wide k-tiles per block (256 cols)

// ws layout in float units
#define INVN_OFF 0
#define Z0_OFF   131072
#define Z1_OFF   196608
#define P0_OFF   262144
#define P1_OFF   327680
#define ZF16_OFF 393216                 // 1024*128 halves = 65536 floats
#define QA_OFF   458752                 // K*D halves = 8388608 floats
#define PVAL_OFF 8847360                // 1024*512 u32
#define IDX_OFF  9371648                // 1024 ints
#define LP_OFF   9372672                // 1024 floats

// Normalize rows of z0, z1, p0, p1 (each B x D) into ws; also z in f16.
__global__ __launch_bounds__(128) void rownorm_k(
    const float* __restrict__ p0, const float* __restrict__ p1,
    const float* __restrict__ z0, const float* __restrict__ z1,
    float* __restrict__ w, _Float16* __restrict__ zf16) {
  int row = blockIdx.x & (B - 1);
  int which = blockIdx.x >> 9;  // 0..3
  const float* src; float* dst;
  switch (which) {
    case 0: src = z0; dst = w + Z0_OFF; break;
    case 1: src = z1; dst = w + Z1_OFF; break;
    case 2: src = p0; dst = w + P0_OFF; break;
    default: src = p1; dst = w + P1_OFF; break;
  }
  int tid = threadIdx.x;
  float v = src[row * D + tid];
  float s = v * v;
  #pragma unroll
  for (int o = 32; o; o >>= 1) s += __shfl_xor(s, o);
  __shared__ float sm[2];
  if ((tid & 63) == 0) sm[tid >> 6] = s;
  __syncthreads();
  float inv = rsqrtf(sm[0] + sm[1]);
  float nv = v * inv;
  dst[row * D + tid] = nv;
  if (which < 2) zf16[(which * B + row) * D + tid] = (_Float16)nv;
}

// Fused, BW-oriented: block owns 128 queue columns.
// Phase 1: float4 loads along k -> column norms (LDS tree reduce).
// Phase 2: L2-hot re-read, coalesced scalar stores of new_queue (f32),
//          stage normalized f16 tile in LDS.
// Phase 3: pack MFMA A-operand fragments (qA) from LDS tile.
// qA frag element i of lane l (g=l>>4, c=l&15), tile ktg, dchunk dc:
//   k = ktg*16 + c ; d = g*4 + (i&3) + ((i>>2)<<4) + dc*32
__global__ __launch_bounds__(256) void colq_k(
    const float* __restrict__ q, const int* __restrict__ qid,
    const int* __restrict__ ids, const float* __restrict__ w_z0,
    float* __restrict__ invn, float* __restrict__ out,
    _Float16* __restrict__ qA) {
  __shared__ float psum[8][128];
  __shared__ float invs[128];
  __shared__ _Float16 tile[128][136];
  int tid = threadIdx.x;
  int kb = blockIdx.x;           // 0..1023
  int k0 = kb * 128;
  {
    int kc = tid & 31, dg = tid >> 5;
    float4 acc = {0.f, 0.f, 0.f, 0.f};
    for (int i = 0; i < 16; i++) {
      int d = dg * 16 + i;
      float4 v = *(const float4*)(q + (size_t)d * K + k0 + kc * 4);
      acc.x = fmaf(v.x, v.x, acc.x); acc.y = fmaf(v.y, v.y, acc.y);
      acc.z = fmaf(v.z, v.z, acc.z); acc.w = fmaf(v.w, v.w, acc.w);
    }
    *(float4*)&psum[dg][kc * 4] = acc;
  }
  __syncthreads();
  if (tid < 128) {
    float s = 0.f;
    #pragma unroll
    for (int g2 = 0; g2 < 8; g2++) s += psum[g2][tid];
    float inv = rsqrtf(s);
    invs[tid] = inv;
    invn[k0 + tid] = inv;
    int kk = k0 + tid;
    out[1 + (size_t)D * K + kk] = (float)((kk < B) ? ids[kk] : qid[kk]);
  }
  __syncthreads();
  {
    int col = tid & 127, dh = tid >> 7;
    float inv = invs[col];
    const float* qc = q + k0 + col;
    float* oc = out + 1 + k0 + col;
    if (k0 < B) {  // whole block's columns come from z0^T (block-uniform)
      const float* zc = w_z0 + (size_t)(k0 + col) * D;
      for (int i = 0; i < 64; i++) {
        int d = dh * 64 + i;
        float o = qc[(size_t)d * K] * inv;
        tile[d][col] = (_Float16)o;       // qA uses normalized OLD queue
        oc[(size_t)d * K] = zc[d];        // output column is z0 row
      }
    } else {
      for (int i = 0; i < 64; i++) {
        int d = dh * 64 + i;
        float o = qc[(size_t)d * K] * inv;
        tile[d][col] = (_Float16)o;
        oc[(size_t)d * K] = o;
      }
    }
  }
  __syncthreads();
  {
    int dc = tid >> 6, l = tid & 63;
    int g = l >> 4, c = l & 15;
    #pragma unroll
    for (int kt = 0; kt < 8; kt++) {
      half8 f;
      #pragma unroll
      for (int i = 0; i < 8; i++) {
        int d = g * 4 + (i & 3) + ((i >> 2) << 4) + dc * 32;
        f[i] = tile[d][kt * 16 + c];
      }
      int ktg = kb * 8 + kt;
      *(half8*)(qA + (size_t)((ktg * 4 + dc) * 64 + l) * 8) = f;
    }
  }
}

#define LOADAF(AF, Q4, KTG) do { \
  _Pragma("unroll") \
  for (int dc = 0; dc < 4; dc++) \
    AF[dc] = *(const half8*)(qA + (size_t)(((KTG) * 4 + dc) * 64 + lane) * 8); \
  Q4 = *(const int4*)(qid + (KTG) * 16 + g * 4); \
} while (0)

#define PROCESS(AF, Q4, KTG) do { \
  int kbase = (KTG) * 16 + g * 4; \
  unsigned idxc0 = 0x1FFFFu - (unsigned)kbase; \
  _Pragma("unroll") \
  for (int nt = 0; nt < 4; nt++) { \
    f32x4 acc = {0.f, 0.f, 0.f, 0.f}; \
    _Pragma("unroll") \
    for (int dc = 0; dc < 4; dc++) \
      acc = __builtin_amdgcn_mfma_f32_16x16x32_f16(AF[dc], bf[nt][dc], acc, 0, 0, 0); \
    _Pragma("unroll") \
    for (int r = 0; r < 4; r++) { \
      float sv_ = acc[r]; \
      int qv_ = (r == 0) ? Q4.x : (r == 1) ? Q4.y : (r == 2) ? Q4.z : Q4.w; \
      float t_ = fmaf(sv_, 0.5f, 3.0f); \
      unsigned pk_ = ((__float_as_uint(t_) << 9) & 0xFFFE0000u) | (idxc0 - r); \
      pk_ = (qv_ == myid[nt]) ? 0u : pk_; \
      best[nt] = best[nt] > pk_ ? best[nt] : pk_; \
    } \
  } \
} while (0)

// MFMA NN search. M = queue index k, N = z-row. Wave owns 64 z-rows
// (B-frags register-resident). Packed-u32 masked argmax; 2-deep pipeline
// on the qA fragment loads.
__global__ __launch_bounds__(256) void nnsearch_k(
    const _Float16* __restrict__ qA, const _Float16* __restrict__ zf16,
    const int* __restrict__ qid, const int* __restrict__ ids,
    unsigned* __restrict__ pbest) {
  int tid = threadIdx.x;
  int kb = blockIdx.x;   // 0..NKB-1
  int rg = blockIdx.y;   // 0..3 (256 rows each)
  int wave = tid >> 6, lane = tid & 63;
  int g = lane >> 4, c = lane & 15;
  int rowbase = rg * 256 + wave * 64;

  half8 bf[4][4];
  int myid[4];
  #pragma unroll
  for (int nt = 0; nt < 4; nt++) {
    int row = rowbase + nt * 16 + c;
    myid[nt] = ids[row & (B - 1)];
    #pragma unroll
    for (int dc = 0; dc < 4; dc++) {
      const _Float16* zr = zf16 + row * D + dc * 32 + g * 4;
      half4 lo = *(const half4*)zr;
      half4 hi = *(const half4*)(zr + 16);
      half8 f = {lo[0], lo[1], lo[2], lo[3], hi[0], hi[1], hi[2], hi[3]};
      bf[nt][dc] = f;
    }
  }

  unsigned best[4] = {0u, 0u, 0u, 0u};
  int kt0 = kb * KT_PER;
  half8 afA[4], afB[4];
  int4 q4A, q4B;
  LOADAF(afA, q4A, kt0);
  for (int kt = 0; kt < KT_PER; kt += 2) {
    LOADAF(afB, q4B, kt0 + kt + 1);
    PROCESS(afA, q4A, kt0 + kt);
    if (kt + 2 < KT_PER) LOADAF(afA, q4A, kt0 + kt + 2);
    PROCESS(afB, q4B, kt0 + kt + 1);
  }

  #pragma unroll
  for (int nt = 0; nt < 4; nt++) {
    unsigned v = best[nt];
    unsigned o1 = __shfl_xor(v, 16); v = v > o1 ? v : o1;
    unsigned o2 = __shfl_xor(v, 32); v = v > o2 ? v : o2;
    if (g == 0) {
      int row = rowbase + nt * 16 + c;
      pbest[row * NKB + kb] = v;
    }
  }
}

// Reduce NKB packed partials per row -> final NN index.
__global__ __launch_bounds__(256) void nnreduce_k(
    const unsigned* __restrict__ pbest, int* __restrict__ idxout) {
  int row = blockIdx.x;
  int tid = threadIdx.x;
  const unsigned* p = pbest + row * NKB;
  unsigned v = p[tid], u = p[tid + 256];
  v = v > u ? v : u;
  #pragma unroll
  for (int o = 32; o; o >>= 1) {
    unsigned ov = __shfl_xor(v, o);
    v = v > ov ? v : ov;
  }
  __shared__ unsigned sv[4];
  if ((tid & 63) == 0) sv[tid >> 6] = v;
  __syncthreads();
  if (tid == 0) {
    #pragma unroll
    for (int wv = 1; wv < 4; wv++) v = v > sv[wv] ? v : sv[wv];
    idxout[row] = (int)(0x1FFFFu - (v & 0x1FFFFu));
  }
}

// Loss: block handles 8 rows (i0..i0+7) for view v. Thread owns columns
// j=tid and j+256 of the 512-wide logits row.
__global__ __launch_bounds__(256) void loss_k(
    const float* __restrict__ q, const float* __restrict__ invn,
    const int* __restrict__ idxout, const float* __restrict__ w,
    float* __restrict__ lpart) {
  int i0 = blockIdx.x * 8;
  int v = blockIdx.y;
  int tid = threadIdx.x;
  __shared__ float nns[8][D];
  __shared__ float rm[8][4], re[8][4], sdlds[8];
  #pragma unroll
  for (int ii = 0; ii < 4; ii++) {
    int i = ii * 2 + (tid >> 7);
    int d = tid & 127;
    int nnidx = idxout[(v ? 0 : B) + i0 + i];
    nns[i][d] = q[(size_t)d * K + nnidx] * invn[nnidx];
  }
  __syncthreads();
  const float* pr = w + (v ? P1_OFF : P0_OFF);
  const float* r0 = pr + tid * D;
  const float* r1 = pr + (tid + 256) * D;
  float a0[8] = {0, 0, 0, 0, 0, 0, 0, 0};
  float a1[8] = {0, 0, 0, 0, 0, 0, 0, 0};
  for (int d = 0; d < D; d += 4) {
    float4 x0 = *(const float4*)(r0 + d);
    float4 x1 = *(const float4*)(r1 + d);
    #pragma unroll
    for (int i = 0; i < 8; i++) {
      float4 n = *(const float4*)&nns[i][d];
      a0[i] = fmaf(x0.x, n.x, a0[i]); a0[i] = fmaf(x0.y, n.y, a0[i]);
      a0[i] = fmaf(x0.z, n.z, a0[i]); a0[i] = fmaf(x0.w, n.w, a0[i]);
      a1[i] = fmaf(x1.x, n.x, a1[i]); a1[i] = fmaf(x1.y, n.y, a1[i]);
      a1[i] = fmaf(x1.z, n.z, a1[i]); a1[i] = fmaf(x1.w, n.w, a1[i]);
    }
  }
  #pragma unroll
  for (int i = 0; i < 8; i++) {
    a0[i] *= (1.0f / TEMP);
    a1[i] *= (1.0f / TEMP);
  }
  #pragma unroll
  for (int i = 0; i < 8; i++) {
    int ig = i0 + i;
    if ((ig & 256) == 0) { if (tid == ig) sdlds[i] = a0[i]; }
    else { if (tid == (ig & 255)) sdlds[i] = a1[i]; }
  }
  int wv = tid >> 6;
  #pragma unroll
  for (int i = 0; i < 8; i++) {
    float m = fmaxf(a0[i], a1[i]);
    #pragma unroll
    for (int o = 32; o; o >>= 1) m = fmaxf(m, __shfl_xor(m, o));
    if ((tid & 63) == 0) rm[i][wv] = m;
  }
  __syncthreads();
  #pragma unroll
  for (int i = 0; i < 8; i++) {
    float m = fmaxf(fmaxf(rm[i][0], rm[i][1]), fmaxf(rm[i][2], rm[i][3]));
    float e = expf(a0[i] - m) + expf(a1[i] - m);
    #pragma unroll
    for (int o = 32; o; o >>= 1) e += __shfl_xor(e, o);
    if ((tid & 63) == 0) re[i][wv] = e;
  }
  __syncthreads();
  if (tid < 8) {
    int i = tid;
    float m = fmaxf(fmaxf(rm[i][0], rm[i][1]), fmaxf(rm[i][2], rm[i][3]));
    float s = re[i][0] + re[i][1] + re[i][2] + re[i][3];
    lpart[v * B + i0 + i] = sdlds[i] - m - logf(s);
  }
}

// Final: loss = -(sum of 1024 partials)/1024 ; also write new_ptr.
__global__ __launch_bounds__(256) void final_k(
    const float* __restrict__ lpart, float* __restrict__ out) {
  int tid = threadIdx.x;
  float s = lpart[tid] + lpart[tid + 256] + lpart[tid + 512] + lpart[tid + 768];
  #pragma unroll
  for (int o = 32; o; o >>= 1) s += __shfl_xor(s, o);
  __shared__ float sm[4];
  if ((tid & 63) == 0) sm[tid >> 6] = s;
  __syncthreads();
  if (tid == 0) {
    float total = sm[0] + sm[1] + sm[2] + sm[3];
    out[0] = -total * (1.0f / 1024.0f);
    out[1 + D * K + K] = 512.0f;
  }
}

extern "C" void kernel_launch(void* const* d_in, const int* in_sizes, int n_in,
                              void* d_out, int out_size, void* d_ws, size_t ws_size,
                              hipStream_t stream) {
  const float* p0 = (const float*)d_in[0];
  const float* p1 = (const float*)d_in[1];
  const float* z0 = (const float*)d_in[2];
  const float* z1 = (const float*)d_in[3];
  const float* q  = (const float*)d_in[4];
  const int* qid  = (const int*)d_in[5];
  const int* ids  = (const int*)d_in[6];
  float* out = (float*)d_out;
  float* w = (float*)d_ws;
  float* invn = w + INVN_OFF;
  _Float16* zf16 = (_Float16*)(w + ZF16_OFF);
  _Float16* qA   = (_Float16*)(w + QA_OFF);
  unsigned* pbest = (unsigned*)(w + PVAL_OFF);
  int* idxout = (int*)(w + IDX_OFF);
  float* lpart = w + LP_OFF;

  rownorm_k<<<2048, 128, 0, stream>>>(p0, p1, z0, z1, w, zf16);
  colq_k<<<K / 128, 256, 0, stream>>>(q, qid, ids, w + Z0_OFF, invn, out, qA);
  dim3 g(NKB, 4);
  nnsearch_k<<<g, 256, 0, stream>>>(qA, zf16, qid, ids, pbest);
  nnreduce_k<<<1024, 256, 0, stream>>>(pbest, idxout);
  dim3 gl(B / 8, 2);
  loss_k<<<gl, 256, 0, stream>>>(q, invn, idxout, w, lpart);
  final_k<<<1, 256, 0, stream>>>(lpart, out);
}